// Round 9
// baseline (401.914 us; speedup 1.0000x reference)
//
#include <hip/hip_runtime.h>
#include <stdint.h>
#include <stddef.h>

#define NROWS 8192
#define DIM   1024
#define RB    512      // fp4 bytes per row (DIM/2)
#define TEMP  10.0f

#define BM 128         // A panel rows per block (64 KB LDS -> 2 blocks/CU)
#define BN 256         // B cols per n-tile (4N waves x 64)

typedef __attribute__((ext_vector_type(4))) int i32x4;
typedef __attribute__((ext_vector_type(8))) int i32x8;
typedef __attribute__((ext_vector_type(16))) float floatx16;

// async 16B global->LDS (global_load_lds_dwordx4); LDS dest is wave-uniform
// base + lane*16 -- all staging dests are slot*16 by construction.
__device__ __forceinline__ void load16_lds(const unsigned char* g, unsigned char* l) {
    __builtin_amdgcn_global_load_lds(
        (__attribute__((address_space(1))) void*)(g),
        (__attribute__((address_space(3))) void*)(l),
        16, 0, 0);
}

// fp4 e2m1 quantize of x (already in grid units, sigma~1): nearest of
// {0,.5,1,1.5,2,3,4,6} with sign. 7-threshold chain, branch-free.
__device__ __forceinline__ unsigned fp4q(float x) {
    float a = fabsf(x);
    a = fminf(a, 6.0f);
    unsigned c = (unsigned)(a >= 0.25f) + (unsigned)(a >= 0.75f)
               + (unsigned)(a >= 1.25f) + (unsigned)(a >= 1.75f)
               + (unsigned)(a >= 2.5f)  + (unsigned)(a >= 3.5f)
               + (unsigned)(a >= 5.0f);
    return c | ((__float_as_uint(x) >> 28) & 8u);
}

// fp4 operand: HW (cbsz=blgp=4) reads only regs 0..3; uppers UNDEF on purpose
// (no zero-movs, no pinned zero registers). Ran verified in r4/r7.
__device__ __forceinline__ i32x8 op8u(i32x4 lo) {
    return __builtin_shufflevector(lo, lo, 0, 1, 2, 3, -1, -1, -1, -1);
}

// ---------------------------------------------------------------------------
// Quantized layout (per matrix, 4 MB) -- MFMA-fragment-linear:
//   element e of row r: chunk c = e>>5 (16B = 32 fp4), it = c>>2,
//   ks = (c>>1)&1, fh = c&1
//   byte = it*524288 + (r>>5)*2048 + ks*1024 + fh*512 + (r&31)*16
// => per (rowgroup, it, ks): 1 KB fragment, lane-linear (lane = fh*32 + fr,
//    16 B per lane). Fragment reads need ZERO address swizzle: LDS frags are
//    ds_read_b128 at base+lane*16+imm (conflict-free), B frags are
//    global_load_dwordx4 at one base + small imm (coalesced 1 KB/wave).
//    A 128-row panel within one it-slab is 8 KB CONTIGUOUS.
// ---------------------------------------------------------------------------

// Wave-per-row L2 normalize + quantize to fp4 e2m1 at fixed scale 2^-5
// (values x32 -> sigma ~1 grid unit). Fragment-linear stores via small LDS
// transpose bounce. (Unchanged since r1; passes.)
__global__ __launch_bounds__(256) void normalize_kernel(
    const float* __restrict__ img, const float* __restrict__ txt,
    unsigned char* __restrict__ imgq, unsigned char* __restrict__ txtq,
    float* __restrict__ out)
{
    __shared__ __align__(16) unsigned short sc[4][256];   // [wave][c*64+lane]
    const int t = threadIdx.x;
    const int lane = t & 63, wave = t >> 6;
    const int gw = blockIdx.x * 4 + wave;                 // row id, 0..16383
    const float* src = (gw < NROWS) ? img + (size_t)gw * DIM
                                    : txt + (size_t)(gw - NROWS) * DIM;
    float4 v[4];
    float ss = 0.f;
#pragma unroll
    for (int c = 0; c < 4; c++) {
        v[c] = ((const float4*)src)[lane + 64 * c];
        ss += v[c].x * v[c].x + v[c].y * v[c].y + v[c].z * v[c].z + v[c].w * v[c].w;
    }
#pragma unroll
    for (int off = 32; off; off >>= 1) ss += __shfl_xor(ss, off);
    const float scale = 32.0f / fmaxf(sqrtf(ss), 1e-12f);   // x32 = fp4 grid
#pragma unroll
    for (int c = 0; c < 4; c++) {
        unsigned p = fp4q(v[c].x * scale)
                   | (fp4q(v[c].y * scale) << 4)
                   | (fp4q(v[c].z * scale) << 8)
                   | (fp4q(v[c].w * scale) << 12);
        sc[wave][c * 64 + lane] = (unsigned short)p;   // ushort u covers elems [4u,4u+4)
    }
    __syncthreads();
    // 128 store units: (rr = row in block 0..3, k = chunk 0..31). Chunk k =
    // ushorts [8k..8k+8) of row rr. 4 consecutive t share (it,ks,fh) and write
    // 4 consecutive fr*16 slots -> 64B-line coalesced.
    if (t < 128) {
        const int rr = t & 3, k = t >> 2;
        const int gr0 = blockIdx.x * 4;      // block never straddles img/txt (4 | 8192)
        unsigned char* dq = (gr0 < NROWS) ? imgq : txtq;
        const int r = (gr0 < NROWS ? gr0 : gr0 - NROWS) + rr;
        const int4 d = *(const int4*)&sc[rr][k * 8];
        const int it = k >> 2, ks = (k >> 1) & 1, fh = k & 1;
        *(int4*)(dq + (size_t)it * 524288 + (size_t)((r >> 5) * 2048
                 + ks * 1024 + fh * 512 + (r & 31) * 16)) = d;
    }
    if (gw == 0 && lane == 0) out[0] = 0.f;   // zero the atomic target
}

// NT-GEMM on fp4 e2m1 via MX-scaled MFMA 32x32x64.
// r7 post-mortem: free-run B-from-global at wave tile 32x64 was bound by the
// per-CU L1 port: 16 waves x 4 KB B per it-step = 64 KB = 1024 cyc vs only
// 566 cyc of MFMA. FLOP per B-byte scales with wave M-rows, so this round
// doubles M: wave tile 64x64 (2M x 4N wave grid, block 128x256). Same port
// traffic per step, but 2x MFMA (1133 cyc/SIMD > port) and HALF the steps
// (32 vs 64). Free-running (r8 proved per-step barriers halve throughput),
// single-buffered fragments; latency hiding by 4-way wave TLP from 2
// independent blocks/CU (LDS = 64 KB A panel only).
// Register plan vs the (512,4) unified 128 cap (measured r7: 64 arch + 32
// acc = 96): now 64 acc + a[2][2]+b[2][2] (32) + addr ~25 => ~121. Fits.
__global__ __launch_bounds__(512, 4) void simloss_kernel(
    const unsigned char* __restrict__ An,   // img fp4, fragment-linear
    const unsigned char* __restrict__ Bn,   // txt fp4, fragment-linear
    const float* __restrict__ bias,
    float* __restrict__ out)
{
    __shared__ __align__(16) unsigned char As[8 * 8192];   // 64 KB A panel

    const int t = threadIdx.x;
    const int lane = t & 63;
    const int wave = t >> 6;            // 0..7

    const int bid = blockIdx.x;         // 0..511
    const int blockM = bid >> 3;        // 0..63
    const int n0 = bid & 7;             // XCD-correlated N strip

    // ---- prologue: DMA the A panel into LDS (8 x 8 KB slabs) ----
    {
        const unsigned char* gA = An + (size_t)blockM * 8192 + t * 16;
#pragma unroll
        for (int it = 0; it < 8; it++)
            load16_lds(gA + (size_t)it * 524288, As + it * 8192 + t * 16);
    }
    asm volatile("s_waitcnt vmcnt(0)" ::: "memory");
    __syncthreads();                    // the only pre-epilogue barrier

    // wave grid 2(M) x 4(N): wave tile 64x64 (mi 0..1, ni 0..1 of 32x32)
    const int rgHalf = wave >> 2;       // 0..1 (A row half: rows rgHalf*64)
    const int nQ = wave & 3;            // 0..3 (cols nQ*64 within 256-tile)
    const int fr = lane & 31;
    const int fh = lane >> 5;
    const int vA0 = rgHalf * 4096 + lane * 16;   // A frag base (rg = 2*rgHalf+mi)

    const float bv = bias[0];
    const float c1 = -TEMP * 1.4426950408889634f / 1024.0f;  // on raw acc
    const float c0 = bv * 1.4426950408889634f;

    // diag: rows [blockM*128,+128) meet cols [n*256,+256) iff n == blockM>>1,
    // which lies in this block's strip iff ((blockM>>1)&7) == n0, at
    // j = (blockM>>1)>>3. All 128 row-diagonals land inside that tile.
    const bool diagAny = ((blockM >> 1) & 7) == n0;
    const int jd = (blockM >> 1) >> 3;

    float accP = 0.f, accQ = 0.f, accD = 0.f;

    for (int j = 0; j < 4; ++j) {       // n-tile sweep: n = n0 + 8j
        const int n = n0 + 8 * j;       // cols [n*256, +256)
        // B rowgroup base for this wave: n*8 + nQ*2 (+ni); frag offsets
        // ni*2048 + ks*1024 within the it-slab.
        const unsigned char* gB = Bn
            + (size_t)((n * 8 + nQ * 2) * 2048 + lane * 16);

        floatx16 acc[2][2];
#pragma unroll
        for (int mi = 0; mi < 2; mi++)
#pragma unroll
            for (int ni = 0; ni < 2; ni++)
                acc[mi][ni] = (floatx16)(0.f);

        for (int it = 0; it < 8; ++it) {
            // issue B first (L2 latency hidden by TLP), then A (LDS), MFMA
            i32x4 b[2][2], a[2][2];     // [ks][ni] / [ks][mi]
#pragma unroll
            for (int ks = 0; ks < 2; ks++)
#pragma unroll
                for (int ni = 0; ni < 2; ni++)
                    b[ks][ni] = *(const i32x4*)(gB + ni * 2048 + ks * 1024);
#pragma unroll
            for (int ks = 0; ks < 2; ks++)
#pragma unroll
                for (int mi = 0; mi < 2; mi++)
                    a[ks][mi] = *(const i32x4*)&As[vA0 + it * 8192
                                                  + mi * 2048 + ks * 1024];
#pragma unroll
            for (int ks = 0; ks < 2; ks++)
#pragma unroll
                for (int mi = 0; mi < 2; mi++)
#pragma unroll
                    for (int ni = 0; ni < 2; ni++)
                        acc[mi][ni] = __builtin_amdgcn_mfma_scale_f32_32x32x64_f8f6f4(
                            op8u(a[ks][mi]), op8u(b[ks][ni]), acc[mi][ni],
                            4, 4,                 // cbsz=blgp=FP4(e2m1)
                            0, 0x7f7f7f7f,        // scale_a = 2^0
                            0, 0x7f7f7f7f);       // scale_b = 2^0
            gB += 524288;
        }

        // ---- epilogue for this 64x64 wave tile. Raw acc = 1024*sim. ----
        // logit = -10*sim + b, x = label*logit;
        //   softplus(x) = (x+|x|)/2 + log(1+e^-|x|);
        //   sum(x)/2 = sum_diag(logit) - sum_all(logit)/2   (linear!)
        // log2 domain, PRODUCT trick: one v_log per 8 logits:
        //   sum log2(1+2^-|w|) = log2( prod (1+2^-|w_i|) ), prod in (1,256].
#pragma unroll
        for (int mi = 0; mi < 2; mi++) {
#pragma unroll
            for (int ni = 0; ni < 2; ni++) {
#pragma unroll
                for (int g = 0; g < 2; g++) {
                    float prod = 1.0f;
#pragma unroll
                    for (int r8 = 0; r8 < 8; r8++) {
                        float sv = acc[mi][ni][g * 8 + r8];   // raw = 1024*sim
                        float w = fmaf(sv, c1, c0);
                        float aw = fabsf(w);
                        prod *= 1.0f + __builtin_amdgcn_exp2f(-aw);
                        accP = fmaf(0.5f, aw, accP);
                        accQ += sv;
                    }
                    accP += __builtin_amdgcn_logf(prod);      // v_log = log2
                }
            }
        }
        if (diagAny && j == jd) {       // n == blockM>>1 here
            const int gi0 = blockM * BM + rgHalf * 64 + 4 * fh;
            const int gj0 = n * BN + nQ * 64 + fr;
#pragma unroll
            for (int mi = 0; mi < 2; mi++)
#pragma unroll
                for (int ni = 0; ni < 2; ni++)
#pragma unroll
                    for (int reg = 0; reg < 16; reg++) {
                        int ig = gi0 + mi * 32 + (reg & 3) + 8 * (reg >> 2);
                        int jg = gj0 + ni * 32;
                        if (ig == jg) accD += acc[mi][ni][reg];
                    }
        }
    }

    // ---- per-wave reduction + atomic (4096 atomics total; r8-verified) ----
#pragma unroll
    for (int off = 32; off; off >>= 1) {
        accP += __shfl_xor(accP, off);
        accQ += __shfl_xor(accQ, off);
        accD += __shfl_xor(accD, off);
    }
    if (lane == 0) {
        // ln2*P + 5*(Qraw/1024) - 10*(Draw/1024); block consts via wave 0:
        // block covers 128x1024 elems -> -(Ne/2)*b = -65536*b; diag +128*b.
        float wcon = fmaf(0.6931471805599453f, accP,
                          fmaf(5.0f / 1024.0f, accQ,
                               (-TEMP / 1024.0f) * accD));
        if (wave == 0)
            wcon += fmaf(-65536.0f, bv, diagAny ? 128.0f * bv : 0.f);
        atomicAdd(out, wcon * (1.0f / 8192.0f));
    }
}

extern "C" void kernel_launch(void* const* d_in, const int* in_sizes, int n_in,
                              void* d_out, int out_size, void* d_ws, size_t ws_size,
                              hipStream_t stream) {
    const float* txt = (const float*)d_in[0];   // text_embeddings [8192][1024]
    const float* img = (const float*)d_in[1];   // image_embeddings [8192][1024]
    const float* bias = (const float*)d_in[2];  // [1]
    float* out = (float*)d_out;

    unsigned char* imgq = (unsigned char*)d_ws;                      // 4 MB fp4
    unsigned char* txtq = imgq + (size_t)NROWS * RB;                 // 4 MB fp4

    normalize_kernel<<<dim3(2 * NROWS / 4), dim3(256), 0, stream>>>(
        img, txt, imgq, txtq, out);

    simloss_kernel<<<dim3((NROWS / BM) * 8), dim3(512), 0, stream>>>(
        imgq, txtq, bias, out);
}

// Round 10
// 235.286 us; speedup vs baseline: 1.7082x; 1.7082x over previous
//
#include <hip/hip_runtime.h>
#include <stdint.h>
#include <stddef.h>

#define NROWS 8192
#define DIM   1024
#define RB    512      // fp4 bytes per row (DIM/2)
#define TEMP  10.0f

#define BM 128         // A panel rows per block (64 KB LDS -> 2 blocks/CU)
#define BN 128         // B cols per n-tile (4N waves x 32)

typedef __attribute__((ext_vector_type(4))) int i32x4;
typedef __attribute__((ext_vector_type(8))) int i32x8;
typedef __attribute__((ext_vector_type(16))) float floatx16;

// async 16B global->LDS (global_load_lds_dwordx4); LDS dest is wave-uniform
// base + lane*16 -- all staging dests are slot*16 by construction.
__device__ __forceinline__ void load16_lds(const unsigned char* g, unsigned char* l) {
    __builtin_amdgcn_global_load_lds(
        (__attribute__((address_space(1))) void*)(g),
        (__attribute__((address_space(3))) void*)(l),
        16, 0, 0);
}

// fp4 e2m1 quantize of x (already in grid units, sigma~1): nearest of
// {0,.5,1,1.5,2,3,4,6} with sign. 7-threshold chain, branch-free.
__device__ __forceinline__ unsigned fp4q(float x) {
    float a = fabsf(x);
    a = fminf(a, 6.0f);
    unsigned c = (unsigned)(a >= 0.25f) + (unsigned)(a >= 0.75f)
               + (unsigned)(a >= 1.25f) + (unsigned)(a >= 1.75f)
               + (unsigned)(a >= 2.5f)  + (unsigned)(a >= 3.5f)
               + (unsigned)(a >= 5.0f);
    return c | ((__float_as_uint(x) >> 28) & 8u);
}

// fp4 operand: HW (cbsz=blgp=4) reads only regs 0..3; uppers UNDEF on purpose
// (no zero-movs, no pinned zero registers). Ran verified in r4/r7.
__device__ __forceinline__ i32x8 op8u(i32x4 lo) {
    return __builtin_shufflevector(lo, lo, 0, 1, 2, 3, -1, -1, -1, -1);
}

// ---------------------------------------------------------------------------
// Quantized layout (per matrix, 4 MB) -- MFMA-fragment-linear:
//   element e of row r: chunk c = e>>5 (16B = 32 fp4), it = c>>2,
//   ks = (c>>1)&1, fh = c&1
//   byte = it*524288 + (r>>5)*2048 + ks*1024 + fh*512 + (r&31)*16
// => per (rowgroup, it, ks): 1 KB fragment, lane-linear (lane = fh*32 + fr,
//    16 B per lane). Fragment reads need ZERO address swizzle: LDS frags are
//    ds_read_b128 at base+lane*16+imm (conflict-free), B frags are
//    global_load_dwordx4 at one base + small imm (coalesced 1 KB/wave).
//    A 128-row panel within one it-slab is 8 KB CONTIGUOUS.
// ---------------------------------------------------------------------------

// Wave-per-row L2 normalize + quantize to fp4 e2m1 at fixed scale 2^-5
// (values x32 -> sigma ~1 grid unit). Fragment-linear stores via small LDS
// transpose bounce. (Unchanged since r1; passes.)
__global__ __launch_bounds__(256) void normalize_kernel(
    const float* __restrict__ img, const float* __restrict__ txt,
    unsigned char* __restrict__ imgq, unsigned char* __restrict__ txtq,
    float* __restrict__ out)
{
    __shared__ __align__(16) unsigned short sc[4][256];   // [wave][c*64+lane]
    const int t = threadIdx.x;
    const int lane = t & 63, wave = t >> 6;
    const int gw = blockIdx.x * 4 + wave;                 // row id, 0..16383
    const float* src = (gw < NROWS) ? img + (size_t)gw * DIM
                                    : txt + (size_t)(gw - NROWS) * DIM;
    float4 v[4];
    float ss = 0.f;
#pragma unroll
    for (int c = 0; c < 4; c++) {
        v[c] = ((const float4*)src)[lane + 64 * c];
        ss += v[c].x * v[c].x + v[c].y * v[c].y + v[c].z * v[c].z + v[c].w * v[c].w;
    }
#pragma unroll
    for (int off = 32; off; off >>= 1) ss += __shfl_xor(ss, off);
    const float scale = 32.0f / fmaxf(sqrtf(ss), 1e-12f);   // x32 = fp4 grid
#pragma unroll
    for (int c = 0; c < 4; c++) {
        unsigned p = fp4q(v[c].x * scale)
                   | (fp4q(v[c].y * scale) << 4)
                   | (fp4q(v[c].z * scale) << 8)
                   | (fp4q(v[c].w * scale) << 12);
        sc[wave][c * 64 + lane] = (unsigned short)p;   // ushort u covers elems [4u,4u+4)
    }
    __syncthreads();
    // 128 store units: (rr = row in block 0..3, k = chunk 0..31). Chunk k =
    // ushorts [8k..8k+8) of row rr. 4 consecutive t share (it,ks,fh) and write
    // 4 consecutive fr*16 slots -> 64B-line coalesced.
    if (t < 128) {
        const int rr = t & 3, k = t >> 2;
        const int gr0 = blockIdx.x * 4;      // block never straddles img/txt (4 | 8192)
        unsigned char* dq = (gr0 < NROWS) ? imgq : txtq;
        const int r = (gr0 < NROWS ? gr0 : gr0 - NROWS) + rr;
        const int4 d = *(const int4*)&sc[rr][k * 8];
        const int it = k >> 2, ks = (k >> 1) & 1, fh = k & 1;
        *(int4*)(dq + (size_t)it * 524288 + (size_t)((r >> 5) * 2048
                 + ks * 1024 + fh * 512 + (r & 31) * 16)) = d;
    }
    if (gw == 0 && lane == 0) out[0] = 0.f;   // zero the atomic target
}

// NT-GEMM on fp4 e2m1 via MX-scaled MFMA 32x32x64.
// r7 (wave 32x64, free-run, 4 waves/SIMD) measured 2009 cyc/step against a
// B-port model of 1024 cyc (16 waves x 4 KB B / ~64 B/cyc L1). FLOP per
// B-byte scales with wave M-rows, so this round swaps the wave tile to
// 64x32 (SAME 32-AGPR acc, SAME 48-reg fragment footprint as r7 -- the
// budget that provably fits (512,4); r4/r9's acc=64 spilled twice):
// B traffic per step halves (32 KB/CU = 512 cyc), MFMA unchanged (566
// cyc/SIMD), A-side LDS reads double but stay cheap (~192 cyc/SIMD-step).
// Clean discriminator: port-bound -> ~28-34 us; latency-bound -> ~53 us
// unchanged and round 11 deepens prefetch instead.
// Everything else identical to r7: free-running (r8: per-step barriers
// halve throughput), A panel resident in 64 KB LDS (2 blocks/CU, 4
// waves/SIMD), even/odd depth-1 prefetch, per-wave atomics.
__global__ __launch_bounds__(512, 4) void simloss_kernel(
    const unsigned char* __restrict__ An,   // img fp4, fragment-linear
    const unsigned char* __restrict__ Bn,   // txt fp4, fragment-linear
    const float* __restrict__ bias,
    float* __restrict__ out)
{
    __shared__ __align__(16) unsigned char As[8 * 8192];   // 64 KB A panel

    const int t = threadIdx.x;
    const int lane = t & 63;
    const int wave = t >> 6;            // 0..7

    const int bid = blockIdx.x;         // 0..511
    const int blockM = bid >> 3;        // 0..63
    const int n0 = bid & 7;             // XCD-correlated N strip

    // ---- prologue: DMA the A panel into LDS (8 x 8 KB slabs) ----
    {
        const unsigned char* gA = An + (size_t)blockM * 8192 + t * 16;
#pragma unroll
        for (int it = 0; it < 8; it++)
            load16_lds(gA + (size_t)it * 524288, As + it * 8192 + t * 16);
    }
    asm volatile("s_waitcnt vmcnt(0)" ::: "memory");
    __syncthreads();                    // the only pre-epilogue barrier

    // wave grid 2(M) x 4(N): wave tile 64x32 (mi 0..1 of 32x32; one 32-col
    // slice nQ per wave)
    const int rgPair = wave >> 2;       // 0..1 (A rows [rgPair*64, +64))
    const int nQ = wave & 3;            // 0..3 (cols [nQ*32, +32) in n-tile)
    const int fr = lane & 31;
    const int fh = lane >> 5;
    const int vA0 = rgPair * 4096 + lane * 16;   // A frag base (rg = 2*rgPair+mi)

    const float bv = bias[0];
    const float c1 = -TEMP * 1.4426950408889634f / 1024.0f;  // on raw acc
    const float c0 = bv * 1.4426950408889634f;

    // diag: rows [blockM*128,+128) meet cols [n*128,+128) iff n == blockM,
    // i.e. (blockM&7)==n0 at j = blockM>>3 (then n = blockM exactly).
    const bool diagAny = (blockM & 7) == n0;
    const int jd = blockM >> 3;

    float accP = 0.f, accQ = 0.f, accD = 0.f;

    for (int j = 0; j < 8; ++j) {       // n-tile sweep: n = n0 + 8j
        const int n = n0 + 8 * j;       // cols [n*128, +128)
        // B rowgroup for this wave's 32-col slice: n*4 + nQ; frag offset
        // ks*1024 within the it-slab.
        const unsigned char* gB = Bn
            + (size_t)((n * 4 + nQ) * 2048 + lane * 16);

        floatx16 acc[2];                // [mi] -- 32 AGPR (the budget that fits)
        acc[0] = (floatx16)(0.f);
        acc[1] = (floatx16)(0.f);

        // depth-1 even/odd pipeline over it = 0..7 (static sets, rule #20)
        // a index = ks*2 + mi; b index = ks.
        i32x4 aE[4], aO[4], bE[2], bO[2];
        // preload it=0 into the even set
#pragma unroll
        for (int ks = 0; ks < 2; ks++) {
#pragma unroll
            for (int mi = 0; mi < 2; mi++)
                aE[ks * 2 + mi] = *(const i32x4*)&As[vA0 + mi * 2048 + ks * 1024];
            bE[ks] = *(const i32x4*)(gB + ks * 1024);
        }

#pragma unroll
        for (int pp = 0; pp < 4; ++pp) {
            // load odd set (it = 2pp+1)
#pragma unroll
            for (int ks = 0; ks < 2; ks++) {
#pragma unroll
                for (int mi = 0; mi < 2; mi++)
                    aO[ks * 2 + mi] = *(const i32x4*)&As[vA0 + (2 * pp + 1) * 8192
                                                        + mi * 2048 + ks * 1024];
                bO[ks] = *(const i32x4*)(gB + (size_t)(2 * pp + 1) * 524288
                                         + ks * 1024);
            }
            // compute even set (it = 2pp)
#pragma unroll
            for (int ks = 0; ks < 2; ks++)
#pragma unroll
                for (int mi = 0; mi < 2; mi++)
                    acc[mi] = __builtin_amdgcn_mfma_scale_f32_32x32x64_f8f6f4(
                        op8u(aE[ks * 2 + mi]), op8u(bE[ks]), acc[mi],
                        4, 4,                 // cbsz=blgp=FP4(e2m1)
                        0, 0x7f7f7f7f,        // scale_a = 2^0
                        0, 0x7f7f7f7f);       // scale_b = 2^0
            // load even set (it = 2pp+2)
            if (pp < 3) {
#pragma unroll
                for (int ks = 0; ks < 2; ks++) {
#pragma unroll
                    for (int mi = 0; mi < 2; mi++)
                        aE[ks * 2 + mi] = *(const i32x4*)&As[vA0 + (2 * pp + 2) * 8192
                                                            + mi * 2048 + ks * 1024];
                    bE[ks] = *(const i32x4*)(gB + (size_t)(2 * pp + 2) * 524288
                                             + ks * 1024);
                }
            }
            // compute odd set (it = 2pp+1)
#pragma unroll
            for (int ks = 0; ks < 2; ks++)
#pragma unroll
                for (int mi = 0; mi < 2; mi++)
                    acc[mi] = __builtin_amdgcn_mfma_scale_f32_32x32x64_f8f6f4(
                        op8u(aO[ks * 2 + mi]), op8u(bO[ks]), acc[mi],
                        4, 4,
                        0, 0x7f7f7f7f,
                        0, 0x7f7f7f7f);
        }

        // ---- epilogue for this 64x32 wave tile. Raw acc = 1024*sim. ----
        // logit = -10*sim + b, x = label*logit;
        //   softplus(x) = (x+|x|)/2 + log(1+e^-|x|);
        //   sum(x)/2 = sum_diag(logit) - sum_all(logit)/2   (linear!)
        // log2 domain, PRODUCT trick: one v_log per 8 logits:
        //   sum log2(1+2^-|w|) = log2( prod (1+2^-|w_i|) ), prod in (1,256].
#pragma unroll
        for (int mi = 0; mi < 2; mi++) {
#pragma unroll
            for (int g = 0; g < 2; g++) {
                float prod = 1.0f;
#pragma unroll
                for (int r8 = 0; r8 < 8; r8++) {
                    float sv = acc[mi][g * 8 + r8];       // raw = 1024*sim
                    float w = fmaf(sv, c1, c0);
                    float aw = fabsf(w);
                    prod *= 1.0f + __builtin_amdgcn_exp2f(-aw);
                    accP = fmaf(0.5f, aw, accP);
                    accQ += sv;
                }
                accP += __builtin_amdgcn_logf(prod);      // v_log = log2
            }
        }
        if (diagAny && j == jd) {       // n == blockM here
            const int gi0 = blockM * BM + rgPair * 64 + 4 * fh;
            const int gj0 = n * BN + nQ * 32 + fr;
#pragma unroll
            for (int mi = 0; mi < 2; mi++)
#pragma unroll
                for (int reg = 0; reg < 16; reg++) {
                    int ig = gi0 + mi * 32 + (reg & 3) + 8 * (reg >> 2);
                    int jg = gj0;
                    if (ig == jg) accD += acc[mi][reg];
                }
        }
    }

    // ---- per-wave reduction + atomic (4096 atomics total; r7-verified) ----
#pragma unroll
    for (int off = 32; off; off >>= 1) {
        accP += __shfl_xor(accP, off);
        accQ += __shfl_xor(accQ, off);
        accD += __shfl_xor(accD, off);
    }
    if (lane == 0) {
        // ln2*P + 5*(Qraw/1024) - 10*(Draw/1024); block consts via wave 0:
        // block covers 128x1024 elems -> -(Ne/2)*b = -65536*b; diag +128*b.
        float wcon = fmaf(0.6931471805599453f, accP,
                          fmaf(5.0f / 1024.0f, accQ,
                               (-TEMP / 1024.0f) * accD));
        if (wave == 0)
            wcon += fmaf(-65536.0f, bv, diagAny ? 128.0f * bv : 0.f);
        atomicAdd(out, wcon * (1.0f / 8192.0f));
    }
}

extern "C" void kernel_launch(void* const* d_in, const int* in_sizes, int n_in,
                              void* d_out, int out_size, void* d_ws, size_t ws_size,
                              hipStream_t stream) {
    const float* txt = (const float*)d_in[0];   // text_embeddings [8192][1024]
    const float* img = (const float*)d_in[1];   // image_embeddings [8192][1024]
    const float* bias = (const float*)d_in[2];  // [1]
    float* out = (float*)d_out;

    unsigned char* imgq = (unsigned char*)d_ws;                      // 4 MB fp4
    unsigned char* txtq = imgq + (size_t)NROWS * RB;                 // 4 MB fp4

    normalize_kernel<<<dim3(2 * NROWS / 4), dim3(256), 0, stream>>>(
        img, txt, imgq, txtq, out);

    simloss_kernel<<<dim3((NROWS / BM) * 8), dim3(512), 0, stream>>>(
        imgq, txtq, bias, out);
}

// Round 11
// 184.696 us; speedup vs baseline: 2.1761x; 1.2739x over previous
//
#include <hip/hip_runtime.h>
#include <stdint.h>
#include <stddef.h>

#define NROWS 8192
#define DIM   1024
#define RB    512      // fp4 bytes per row (DIM/2)
#define TEMP  10.0f

#define BM 128         // A panel rows per block (64 KB LDS -> 2 blocks/CU)
#define BN 128         // B cols per n-tile

typedef __attribute__((ext_vector_type(4))) int i32x4;
typedef __attribute__((ext_vector_type(8))) int i32x8;
typedef __attribute__((ext_vector_type(16))) float floatx16;

// async 16B global->LDS (global_load_lds_dwordx4); LDS dest is wave-uniform
// base + lane*16 -- all staging dests are slot*16 by construction.
__device__ __forceinline__ void load16_lds(const unsigned char* g, unsigned char* l) {
    __builtin_amdgcn_global_load_lds(
        (__attribute__((address_space(1))) void*)(g),
        (__attribute__((address_space(3))) void*)(l),
        16, 0, 0);
}

// fp4 e2m1 quantize of x (already in grid units, sigma~1): nearest of
// {0,.5,1,1.5,2,3,4,6} with sign. 7-threshold chain, branch-free.
__device__ __forceinline__ unsigned fp4q(float x) {
    float a = fabsf(x);
    a = fminf(a, 6.0f);
    unsigned c = (unsigned)(a >= 0.25f) + (unsigned)(a >= 0.75f)
               + (unsigned)(a >= 1.25f) + (unsigned)(a >= 1.75f)
               + (unsigned)(a >= 2.5f)  + (unsigned)(a >= 3.5f)
               + (unsigned)(a >= 5.0f);
    return c | ((__float_as_uint(x) >> 28) & 8u);
}

// fp4 operand: HW (cbsz=blgp=4) reads only regs 0..3; uppers UNDEF on purpose
// (no zero-movs, no pinned zero registers). Ran verified in r4/r7.
__device__ __forceinline__ i32x8 op8u(i32x4 lo) {
    return __builtin_shufflevector(lo, lo, 0, 1, 2, 3, -1, -1, -1, -1);
}

// ---------------------------------------------------------------------------
// Quantized layout (per matrix, 4 MB) -- MFMA-fragment-linear:
//   element e of row r: chunk c = e>>5 (16B = 32 fp4), it = c>>2,
//   ks = (c>>1)&1, fh = c&1
//   byte = it*524288 + (r>>5)*2048 + ks*1024 + fh*512 + (r&31)*16
// => per (rowgroup, it, ks): 1 KB fragment, lane-linear (lane = fh*32 + fr,
//    16 B per lane). Fragment reads need ZERO address swizzle: LDS frags are
//    ds_read_b128 at base+lane*16+imm (conflict-free), B frags are
//    global_load_dwordx4 at one bumped base + small imm (coalesced 1 KB/wave).
//    A 128-row panel within one it-slab is 8 KB CONTIGUOUS.
// ---------------------------------------------------------------------------

// ---- r11 helpers: statically-named operand sets (rule #20), inlined ----
__device__ __forceinline__ void bpre(i32x4 (&dst)[4], const unsigned char*& gBp) {
#pragma unroll
    for (int q = 0; q < 4; q++)
        dst[q] = *(const i32x4*)(gBp + (q & 1) * 2048 + (q >> 1) * 1024);
    gBp += 524288;                      // next it-slab
}
__device__ __forceinline__ void apre(i32x4 (&dst)[2], const unsigned char* AsA, int off) {
#pragma unroll
    for (int ks = 0; ks < 2; ks++)
        dst[ks] = *(const i32x4*)(AsA + off + ks * 1024);
}
__device__ __forceinline__ void comp(floatx16 (&acc)[2], const i32x4 (&a)[2],
                                     const i32x4 (&b)[4]) {
#pragma unroll
    for (int ks = 0; ks < 2; ks++)
#pragma unroll
        for (int ni = 0; ni < 2; ni++)
            acc[ni] = __builtin_amdgcn_mfma_scale_f32_32x32x64_f8f6f4(
                op8u(a[ks]), op8u(b[ks * 2 + ni]), acc[ni],
                4, 4,                 // cbsz=blgp=FP4(e2m1)
                0, 0x7f7f7f7f,        // scale_a = 2^0
                0, 0x7f7f7f7f);       // scale_b = 2^0
}

// Wave-per-row L2 normalize + quantize to fp4 e2m1 at fixed scale 2^-5
// (values x32 -> sigma ~1 grid unit). Fragment-linear stores via small LDS
// transpose bounce. (Unchanged since r1; passes.)
__global__ __launch_bounds__(256) void normalize_kernel(
    const float* __restrict__ img, const float* __restrict__ txt,
    unsigned char* __restrict__ imgq, unsigned char* __restrict__ txtq,
    float* __restrict__ out)
{
    __shared__ __align__(16) unsigned short sc[4][256];   // [wave][c*64+lane]
    const int t = threadIdx.x;
    const int lane = t & 63, wave = t >> 6;
    const int gw = blockIdx.x * 4 + wave;                 // row id, 0..16383
    const float* src = (gw < NROWS) ? img + (size_t)gw * DIM
                                    : txt + (size_t)(gw - NROWS) * DIM;
    float4 v[4];
    float ss = 0.f;
#pragma unroll
    for (int c = 0; c < 4; c++) {
        v[c] = ((const float4*)src)[lane + 64 * c];
        ss += v[c].x * v[c].x + v[c].y * v[c].y + v[c].z * v[c].z + v[c].w * v[c].w;
    }
#pragma unroll
    for (int off = 32; off; off >>= 1) ss += __shfl_xor(ss, off);
    const float scale = 32.0f / fmaxf(sqrtf(ss), 1e-12f);   // x32 = fp4 grid
#pragma unroll
    for (int c = 0; c < 4; c++) {
        unsigned p = fp4q(v[c].x * scale)
                   | (fp4q(v[c].y * scale) << 4)
                   | (fp4q(v[c].z * scale) << 8)
                   | (fp4q(v[c].w * scale) << 12);
        sc[wave][c * 64 + lane] = (unsigned short)p;   // ushort u covers elems [4u,4u+4)
    }
    __syncthreads();
    // 128 store units: (rr = row in block 0..3, k = chunk 0..31). Chunk k =
    // ushorts [8k..8k+8) of row rr. 4 consecutive t share (it,ks,fh) and write
    // 4 consecutive fr*16 slots -> 64B-line coalesced.
    if (t < 128) {
        const int rr = t & 3, k = t >> 2;
        const int gr0 = blockIdx.x * 4;      // block never straddles img/txt (4 | 8192)
        unsigned char* dq = (gr0 < NROWS) ? imgq : txtq;
        const int r = (gr0 < NROWS ? gr0 : gr0 - NROWS) + rr;
        const int4 d = *(const int4*)&sc[rr][k * 8];
        const int it = k >> 2, ks = (k >> 1) & 1, fh = k & 1;
        *(int4*)(dq + (size_t)it * 524288 + (size_t)((r >> 5) * 2048
                 + ks * 1024 + fh * 512 + (r & 31) * 16)) = d;
    }
    if (gw == 0 && lane == 0) out[0] = 0.f;   // zero the atomic target
}

// NT-GEMM on fp4 e2m1 via MX-scaled MFMA 32x32x64.
// r10 post-mortem: r2 (2w/SIMD, 32 KB B/CU-step) and r7 (4w/SIMD, 64 KB)
// both measure ~2000 cyc/step -> NOT port-bound. MfmaUtil 25 + VALUBusy 31
// leaves ~44% of cycles with neither pipe issuing: L1-miss latency on the
// depth-1 B prefetch (free-drifting waves blow the 32 KB L1; L2 round trip
// 200-500 cyc > the ~150-300 cyc cover). This round = r7 VERBATIM (the only
// 4w/SIMD register arrangement proven to fit (512,4): r4/r9/r10 all spilled
// on variations) + ONE change: B prefetch depth 1 -> 2 via three rotating
// statically-named sets b0/b1/b2 (+16 regs; ~111 total, real margin), with
// a single bumped prefetch pointer so all loads are base+imm.
__global__ __launch_bounds__(512, 4) void simloss_kernel(
    const unsigned char* __restrict__ An,   // img fp4, fragment-linear
    const unsigned char* __restrict__ Bn,   // txt fp4, fragment-linear
    const float* __restrict__ bias,
    float* __restrict__ out)
{
    __shared__ __align__(16) unsigned char As[8 * 8192];   // 64 KB A panel

    const int t = threadIdx.x;
    const int lane = t & 63;
    const int wave = t >> 6;            // 0..7

    const int bid = blockIdx.x;         // 0..511
    const int blockM = bid >> 3;        // 0..63
    const int n0 = bid & 7;             // XCD-correlated N strip

    // ---- prologue: DMA the A panel into LDS (8 x 8 KB slabs) ----
    {
        const unsigned char* gA = An + (size_t)blockM * 8192 + t * 16;
#pragma unroll
        for (int it = 0; it < 8; it++)
            load16_lds(gA + (size_t)it * 524288, As + it * 8192 + t * 16);
    }
    asm volatile("s_waitcnt vmcnt(0)" ::: "memory");
    __syncthreads();                    // the only pre-epilogue barrier

    // wave grid 4(M) x 2(N): rows = rgHalf*32, cols = nHalf*64 within tile
    const int rgHalf = wave >> 1;       // 0..3 (A rowgroup)
    const int nHalf = wave & 1;         // 0..1
    const int fr = lane & 31;
    const int fh = lane >> 5;
    const unsigned char* AsA = (const unsigned char*)As
                             + (rgHalf * 2048 + lane * 16);   // A frag base

    const float bv = bias[0];
    const float c1 = -TEMP * 1.4426950408889634f / 1024.0f;  // on raw acc
    const float c0 = bv * 1.4426950408889634f;

    // diag: rows [blockM*128,+128) meet cols [n*128,+128) iff n == blockM,
    // i.e. (blockM&7)==n0 at j = blockM>>3 (then n = blockM exactly).
    const bool diagAny = (blockM & 7) == n0;
    const int jd = blockM >> 3;

    float accP = 0.f, accQ = 0.f, accD = 0.f;

    for (int j = 0; j < 8; ++j) {       // n-tile sweep: n = n0 + 8j
        const int n = n0 + 8 * j;       // cols [n*128, +128)
        const unsigned char* gBp = Bn
            + (size_t)((n * 4 + nHalf * 2) * 2048 + lane * 16);

        floatx16 acc[2];
        acc[0] = (floatx16)(0.f);
        acc[1] = (floatx16)(0.f);

        // depth-2 B pipeline (b0/b1/b2 rotate), depth-1 A even/odd.
        i32x4 aE[2], aO[2], b0[4], b1[4], b2[4];
        bpre(b0, gBp);                  // it 0
        bpre(b1, gBp);                  // it 1
        apre(aE, AsA, 0);               // it 0

        // steps it = 0..7: prefetch B(it+2), A(it+1), compute(it)
        bpre(b2, gBp); apre(aO, AsA, 1 * 8192); comp(acc, aE, b0);   // it 0
        bpre(b0, gBp); apre(aE, AsA, 2 * 8192); comp(acc, aO, b1);   // it 1
        bpre(b1, gBp); apre(aO, AsA, 3 * 8192); comp(acc, aE, b2);   // it 2
        bpre(b2, gBp); apre(aE, AsA, 4 * 8192); comp(acc, aO, b0);   // it 3
        bpre(b0, gBp); apre(aO, AsA, 5 * 8192); comp(acc, aE, b1);   // it 4
        bpre(b1, gBp); apre(aE, AsA, 6 * 8192); comp(acc, aO, b2);   // it 5
                       apre(aO, AsA, 7 * 8192); comp(acc, aE, b0);   // it 6
                                                comp(acc, aO, b1);   // it 7

        // ---- epilogue for this 32x64 wave tile. Raw acc = 1024*sim. ----
        // logit = -10*sim + b, x = label*logit;
        //   softplus(x) = (x+|x|)/2 + log(1+e^-|x|);
        //   sum(x)/2 = sum_diag(logit) - sum_all(logit)/2   (linear!)
        // log2 domain, PRODUCT trick: one v_log per 8 logits:
        //   sum log2(1+2^-|w|) = log2( prod (1+2^-|w_i|) ), prod in (1,256].
#pragma unroll
        for (int ni = 0; ni < 2; ni++) {
#pragma unroll
            for (int g = 0; g < 2; g++) {
                float prod = 1.0f;
#pragma unroll
                for (int r8 = 0; r8 < 8; r8++) {
                    float sv = acc[ni][g * 8 + r8];       // raw = 1024*sim
                    float w = fmaf(sv, c1, c0);
                    float aw = fabsf(w);
                    prod *= 1.0f + __builtin_amdgcn_exp2f(-aw);
                    accP = fmaf(0.5f, aw, accP);
                    accQ += sv;
                }
                accP += __builtin_amdgcn_logf(prod);      // v_log = log2
            }
        }
        if (diagAny && j == jd) {       // n == blockM here
            const int gi0 = blockM * BM + rgHalf * 32 + 4 * fh;
            const int gj0 = n * BN + nHalf * 64 + fr;
#pragma unroll
            for (int ni = 0; ni < 2; ni++)
#pragma unroll
                for (int reg = 0; reg < 16; reg++) {
                    int ig = gi0 + (reg & 3) + 8 * (reg >> 2);
                    int jg = gj0 + ni * 32;
                    if (ig == jg) accD += acc[ni][reg];
                }
        }
    }

    // ---- per-wave reduction + atomic (4096 atomics total; r7-verified) ----
#pragma unroll
    for (int off = 32; off; off >>= 1) {
        accP += __shfl_xor(accP, off);
        accQ += __shfl_xor(accQ, off);
        accD += __shfl_xor(accD, off);
    }
    if (lane == 0) {
        // ln2*P + 5*(Qraw/1024) - 10*(Draw/1024); block consts via wave 0:
        // block covers 128x1024 elems -> -(Ne/2)*b = -65536*b; diag +128*b.
        float wcon = fmaf(0.6931471805599453f, accP,
                          fmaf(5.0f / 1024.0f, accQ,
                               (-TEMP / 1024.0f) * accD));
        if (wave == 0)
            wcon += fmaf(-65536.0f, bv, diagAny ? 128.0f * bv : 0.f);
        atomicAdd(out, wcon * (1.0f / 8192.0f));
    }
}

extern "C" void kernel_launch(void* const* d_in, const int* in_sizes, int n_in,
                              void* d_out, int out_size, void* d_ws, size_t ws_size,
                              hipStream_t stream) {
    const float* txt = (const float*)d_in[0];   // text_embeddings [8192][1024]
    const float* img = (const float*)d_in[1];   // image_embeddings [8192][1024]
    const float* bias = (const float*)d_in[2];  // [1]
    float* out = (float*)d_out;

    unsigned char* imgq = (unsigned char*)d_ws;                      // 4 MB fp4
    unsigned char* txtq = imgq + (size_t)NROWS * RB;                 // 4 MB fp4

    normalize_kernel<<<dim3(2 * NROWS / 4), dim3(256), 0, stream>>>(
        img, txt, imgq, txtq, out);

    simloss_kernel<<<dim3((NROWS / BM) * 8), dim3(512), 0, stream>>>(
        imgq, txtq, bias, out);
}